// Round 1
// baseline (17488.269 us; speedup 1.0000x reference)
//
#include <hip/hip_runtime.h>

#define BB 128   // batch
#define LL 512   // seq len
#define HH 2048  // hidden
#define EE 128   // embed
#define VV 96    // vocab
#define BBHH (BB * HH)

typedef short bf16x8 __attribute__((ext_vector_type(8)));
typedef float f32x4 __attribute__((ext_vector_type(4)));

__device__ __forceinline__ unsigned short f2bf(float f) {
    union { float f; unsigned int u; } c; c.f = f;
    unsigned int u = c.u;
    return (unsigned short)((u + 0x7FFFu + ((u >> 16) & 1u)) >> 16);  // RNE
}

// ---------------------------------------------------------------------------
// Setup: identical packing to the proven kernel (W_hh / W_hy -> MFMA-B
// fragment-linear bf16 tiles; projE fp32; h0 -> bf16) + zero the 8 group
// barrier counters.
// ---------------------------------------------------------------------------
__global__ __launch_bounds__(256)
void setup_kernel(const int* __restrict__ x, const float* __restrict__ hidden,
                  const float* __restrict__ emb, const float* __restrict__ W_xh,
                  const float* __restrict__ W_hh, const float* __restrict__ b_h,
                  const float* __restrict__ W_hy,
                  float* __restrict__ projE,
                  unsigned short* __restrict__ w_hh_frag,
                  unsigned short* __restrict__ w_hy_frag,
                  unsigned short* __restrict__ hbuf,
                  unsigned int* __restrict__ bar)
{
    const int gtid = blockIdx.x * 256 + threadIdx.x;
    const int GT   = gridDim.x * 256;

    if (gtid < 8) bar[gtid] = 0u;   // group barrier counters (reset every run)

    for (int idx = gtid; idx < HH * HH; idx += GT) {
        int tile = idx >> 15;
        int rem  = idx & 32767;
        int c    = rem >> 3;
        int j    = rem & 7;
        int l    = c & 63;
        int i    = c >> 6;
        int row  = tile * 16 + (l & 15);
        int k    = i * 32 + (l >> 4) * 8 + j;
        w_hh_frag[idx] = f2bf(W_hh[(size_t)row * HH + k]);
    }
    for (int idx = gtid; idx < VV * HH; idx += GT) {
        int tile = idx >> 15;
        int rem  = idx & 32767;
        int c    = rem >> 3;
        int j    = rem & 7;
        int l    = c & 63;
        int i    = c >> 6;
        int row  = tile * 16 + (l & 15);
        int k    = i * 32 + (l >> 4) * 8 + j;
        w_hy_frag[idx] = f2bf(W_hy[(size_t)row * HH + k]);
    }
    for (int i = gtid; i < VV * HH; i += GT) {
        int v  = i >> 11;
        int hc = i & (HH - 1);
        const float4* ep = (const float4*)(emb + (size_t)v * EE);
        const float4* wp = (const float4*)(W_xh + (size_t)hc * EE);
        float s = b_h[hc];
        #pragma unroll 8
        for (int e = 0; e < EE / 4; ++e) {
            float4 a = ep[e], b = wp[e];
            s += a.x * b.x + a.y * b.y + a.z * b.z + a.w * b.w;
        }
        projE[i] = s;
    }
    for (int i = gtid; i < BBHH; i += GT) hbuf[i] = f2bf(hidden[i]);
}

// ---------------------------------------------------------------------------
// Persistent cooperative kernel. Grid 256 blocks x 512 threads (8 waves),
// 1 block/CU. Group g = bid>>5 owns batch rows 16g..16g+15 (independent
// recurrence chain); its 32 blocks each own 64 hidden cols and sync per step
// via an agent-scope atomic counter + threadfence (cross-XCD release/acquire).
// W_hh slice lives in VGPRs for the whole run: wave w (K-split 8, K-chunks
// w*8..w*8+7) holds breg[4][8] = 128 VGPRs. Duty blocks (cb<6) also hold
// their 16-col W_hy slice (wreg[8], +32 VGPRs) and emit logits for t-1.
// ---------------------------------------------------------------------------
__global__ __launch_bounds__(512, 2)
void rnn_persist(const int* __restrict__ x, const float* __restrict__ projE,
                 const unsigned short* __restrict__ w_hh_frag,
                 const unsigned short* __restrict__ w_hy_frag,
                 const float* __restrict__ b_y,
                 unsigned short* __restrict__ hbuf,
                 float* __restrict__ out_logits, float* __restrict__ out_final,
                 unsigned int* __restrict__ bar)
{
    const int tid  = threadIdx.x;
    const int bid  = blockIdx.x;
    const int g    = bid >> 5;        // group 0..7 (16 batch rows)
    const int cb   = bid & 31;        // col-block 0..31 (64 hidden cols)
    const int r0   = g * 16;
    const int c0   = cb * 64;

    const int w    = tid >> 6;        // wave 0..7 = K-split index
    const int lane = tid & 63;
    const int col  = lane & 15;
    const int q    = lane >> 4;
    const int am   = r0 + col;        // A-fragment row (batch index)

    const bool duty = (cb < 6);

    __shared__ f32x4 part [8][4][64]; // 32 KB h partials
    __shared__ f32x4 partL[8][64];    //  8 KB logits partials

    // ---- persistent W_hh fragments in registers (static indexing only) ----
    bf16x8 breg[4][8];
    {
        const bf16x8* Wc = (const bf16x8*)w_hh_frag;
        #pragma unroll
        for (int n = 0; n < 4; ++n) {
            const bf16x8* Bt = Wc + (size_t)(cb * 4 + n) * 4096 + lane;
            #pragma unroll
            for (int j = 0; j < 8; ++j) breg[n][j] = Bt[(w * 8 + j) * 64];
        }
    }
    bf16x8 wreg[8];
    if (duty) {
        const bf16x8* Bt = (const bf16x8*)w_hy_frag + (size_t)cb * 4096 + lane;
        #pragma unroll
        for (int j = 0; j < 8; ++j) wreg[j] = Bt[(w * 8 + j) * 64];
    }

    unsigned int* ctr = bar + g;

    for (int t = 0; t < LL; ++t) {
        const unsigned short* hp = hbuf + (size_t)(t & 1) * BBHH;
        unsigned short*       hn = hbuf + (size_t)((t + 1) & 1) * BBHH;

        // A fragments for this wave's K-range (rows r0..r0+15 of h_t)
        const bf16x8* Ap = (const bf16x8*)(hp + (size_t)am * HH);
        bf16x8 a[8];
        #pragma unroll
        for (int j = 0; j < 8; ++j) a[j] = Ap[(w * 8 + j) * 4 + q];

        f32x4 acc0 = {0.f,0.f,0.f,0.f}, acc1 = {0.f,0.f,0.f,0.f};
        f32x4 acc2 = {0.f,0.f,0.f,0.f}, acc3 = {0.f,0.f,0.f,0.f};
        f32x4 accL = {0.f,0.f,0.f,0.f};
        #pragma unroll
        for (int j = 0; j < 8; ++j) {   // 4 independent chains of 8
            acc0 = __builtin_amdgcn_mfma_f32_16x16x32_bf16(a[j], breg[0][j], acc0, 0, 0, 0);
            acc1 = __builtin_amdgcn_mfma_f32_16x16x32_bf16(a[j], breg[1][j], acc1, 0, 0, 0);
            acc2 = __builtin_amdgcn_mfma_f32_16x16x32_bf16(a[j], breg[2][j], acc2, 0, 0, 0);
            acc3 = __builtin_amdgcn_mfma_f32_16x16x32_bf16(a[j], breg[3][j], acc3, 0, 0, 0);
        }
        if (duty) {
            #pragma unroll
            for (int j = 0; j < 8; ++j)
                accL = __builtin_amdgcn_mfma_f32_16x16x32_bf16(a[j], wreg[j], accL, 0, 0, 0);
        }

        part[w][0][lane] = acc0; part[w][1][lane] = acc1;
        part[w][2][lane] = acc2; part[w][3][lane] = acc3;
        if (duty) partL[w][lane] = accL;
        __syncthreads();

        if (w < 4) {
            // reduce K-split partials for tile n=w, then epilogue
            f32x4 s = part[0][w][lane];
            #pragma unroll
            for (int k = 1; k < 8; ++k) s += part[k][w][lane];
            const int ccol = c0 + w * 16 + col;
            #pragma unroll
            for (int r = 0; r < 4; ++r) {
                int row = r0 + q * 4 + r;
                int tok = x[(size_t)row * LL + t];
                float v = s[r] + projE[(size_t)tok * HH + ccol];
                v = fminf(fmaxf(v, -15.f), 15.f);
                float e2 = __expf(2.f * v);
                float hv = (e2 - 1.f) / (e2 + 1.f);   // tanh
                hn[(size_t)row * HH + ccol] = f2bf(hv);
                if (t == LL - 1) out_final[(size_t)row * HH + ccol] = hv;
            }
        } else if (w == 4 && duty && t > 0) {
            // logits for position t-1 from h_t == hp
            f32x4 s = partL[0][lane];
            #pragma unroll
            for (int k = 1; k < 8; ++k) s += partL[k][lane];
            const int lcol = cb * 16 + col;
            float by = b_y[lcol];
            #pragma unroll
            for (int r = 0; r < 4; ++r) {
                int row = r0 + q * 4 + r;
                out_logits[(size_t)row * (LL * VV) + (size_t)(t - 1) * VV + lcol]
                    = s[r] + by;
            }
        }

        // ---- group barrier: release stores, arrive, wait, acquire ----
        __syncthreads();                 // drains each wave's vmcnt (stores in L2)
        if (tid == 0) {
            __threadfence();             // wbL2: release our XCD's writes to L3
            __hip_atomic_fetch_add(ctr, 1u, __ATOMIC_RELEASE, __HIP_MEMORY_SCOPE_AGENT);
            const unsigned int tgt = 32u * (unsigned int)(t + 1);
            while (__hip_atomic_load(ctr, __ATOMIC_RELAXED, __HIP_MEMORY_SCOPE_AGENT) < tgt)
                __builtin_amdgcn_s_sleep(2);
            __threadfence();             // invL2/L1: acquire fresh h from L3
        }
        __syncthreads();
    }

    // final logits (position LL-1) from s_512, which sits in ping buffer 0
    if (duty) {
        const bf16x8* Ap = (const bf16x8*)(hbuf + (size_t)am * HH);
        bf16x8 a[8];
        #pragma unroll
        for (int j = 0; j < 8; ++j) a[j] = Ap[(w * 8 + j) * 4 + q];
        f32x4 accL = {0.f,0.f,0.f,0.f};
        #pragma unroll
        for (int j = 0; j < 8; ++j)
            accL = __builtin_amdgcn_mfma_f32_16x16x32_bf16(a[j], wreg[j], accL, 0, 0, 0);
        partL[w][lane] = accL;
        __syncthreads();
        if (w == 4) {
            f32x4 s = partL[0][lane];
            #pragma unroll
            for (int k = 1; k < 8; ++k) s += partL[k][lane];
            const int lcol = cb * 16 + col;
            float by = b_y[lcol];
            #pragma unroll
            for (int r = 0; r < 4; ++r) {
                int row = r0 + q * 4 + r;
                out_logits[(size_t)row * (LL * VV) + (size_t)(LL - 1) * VV + lcol]
                    = s[r] + by;
            }
        }
    }
}

extern "C" void kernel_launch(void* const* d_in, const int* in_sizes, int n_in,
                              void* d_out, int out_size, void* d_ws, size_t ws_size,
                              hipStream_t stream) {
    const int*   x      = (const int*)  d_in[0];
    const float* hidden = (const float*)d_in[1];
    const float* emb    = (const float*)d_in[2];
    const float* W_xh   = (const float*)d_in[3];
    const float* W_hh   = (const float*)d_in[4];
    const float* b_h    = (const float*)d_in[5];
    const float* W_hy   = (const float*)d_in[6];
    const float* b_y    = (const float*)d_in[7];

    float* out_logits = (float*)d_out;                          // [B][L][V]
    float* out_final  = out_logits + (size_t)BB * LL * VV;      // [B][H]

    // workspace layout (10.38 MB): whh_frag 8 MB | why_frag 384 KB |
    // projE 768 KB | h ping-pong 1 MB | 8 barrier counters
    char* ws = (char*)d_ws;
    unsigned short* w_hh_frag = (unsigned short*)ws;
    unsigned short* w_hy_frag = (unsigned short*)(ws + 8388608);
    float*          projE     = (float*)        (ws + 8388608 + 393216);
    unsigned short* hbuf      = (unsigned short*)(ws + 8388608 + 393216 + 786432);
    unsigned int*   bar       = (unsigned int*) (ws + 8388608 + 393216 + 786432 + 1048576);

    setup_kernel<<<dim3(1024), dim3(256), 0, stream>>>(
        x, hidden, emb, W_xh, W_hh, b_h, W_hy,
        projE, w_hh_frag, w_hy_frag, hbuf, bar);

    void* args[] = { (void*)&x, (void*)&projE, (void*)&w_hh_frag, (void*)&w_hy_frag,
                     (void*)&b_y, (void*)&hbuf, (void*)&out_logits, (void*)&out_final,
                     (void*)&bar };
    hipLaunchCooperativeKernel((void*)rnn_persist, dim3(256), dim3(512),
                               args, 0, stream);
}

// Round 2
// 3456.195 us; speedup vs baseline: 5.0600x; 5.0600x over previous
//
#include <hip/hip_runtime.h>

#define BB 128   // batch
#define LL 512   // seq len
#define HH 2048  // hidden
#define EE 128   // embed
#define VV 96    // vocab
#define BBHH (BB * HH)

typedef short bf16x8 __attribute__((ext_vector_type(8)));
typedef float f32x4 __attribute__((ext_vector_type(4)));

__device__ __forceinline__ unsigned short f2bf(float f) {
    union { float f; unsigned int u; } c; c.f = f;
    unsigned int u = c.u;
    return (unsigned short)((u + 0x7FFFu + ((u >> 16) & 1u)) >> 16);  // RNE
}

// ---------------------------------------------------------------------------
// Setup: identical packing to the proven kernel (W_hh / W_hy -> MFMA-B
// fragment-linear bf16 tiles; projE fp32; h0 -> bf16) + zero the padded
// group barrier counters (8 groups x 128 B spacing).
// ---------------------------------------------------------------------------
__global__ __launch_bounds__(256)
void setup_kernel(const int* __restrict__ x, const float* __restrict__ hidden,
                  const float* __restrict__ emb, const float* __restrict__ W_xh,
                  const float* __restrict__ W_hh, const float* __restrict__ b_h,
                  const float* __restrict__ W_hy,
                  float* __restrict__ projE,
                  unsigned short* __restrict__ w_hh_frag,
                  unsigned short* __restrict__ w_hy_frag,
                  unsigned short* __restrict__ hbuf,
                  unsigned int* __restrict__ bar)
{
    const int gtid = blockIdx.x * 256 + threadIdx.x;
    const int GT   = gridDim.x * 256;

    if (gtid < 8 * 32) bar[gtid] = 0u;   // padded counters, reset every run

    for (int idx = gtid; idx < HH * HH; idx += GT) {
        int tile = idx >> 15;
        int rem  = idx & 32767;
        int c    = rem >> 3;
        int j    = rem & 7;
        int l    = c & 63;
        int i    = c >> 6;
        int row  = tile * 16 + (l & 15);
        int k    = i * 32 + (l >> 4) * 8 + j;
        w_hh_frag[idx] = f2bf(W_hh[(size_t)row * HH + k]);
    }
    for (int idx = gtid; idx < VV * HH; idx += GT) {
        int tile = idx >> 15;
        int rem  = idx & 32767;
        int c    = rem >> 3;
        int j    = rem & 7;
        int l    = c & 63;
        int i    = c >> 6;
        int row  = tile * 16 + (l & 15);
        int k    = i * 32 + (l >> 4) * 8 + j;
        w_hy_frag[idx] = f2bf(W_hy[(size_t)row * HH + k]);
    }
    for (int i = gtid; i < VV * HH; i += GT) {
        int v  = i >> 11;
        int hc = i & (HH - 1);
        const float4* ep = (const float4*)(emb + (size_t)v * EE);
        const float4* wp = (const float4*)(W_xh + (size_t)hc * EE);
        float s = b_h[hc];
        #pragma unroll 8
        for (int e = 0; e < EE / 4; ++e) {
            float4 a = ep[e], b = wp[e];
            s += a.x * b.x + a.y * b.y + a.z * b.z + a.w * b.w;
        }
        projE[i] = s;
    }
    for (int i = gtid; i < BBHH; i += GT) hbuf[i] = f2bf(hidden[i]);
}

// ---------------------------------------------------------------------------
// Persistent cooperative kernel, v2. Same decomposition as round 1 (group
// g = bid>>5 owns 16 batch rows; 32 col-blocks of 64 hidden cols; 8 waves
// K-split W_hh held in registers). Coherence redesign: NO threadfence / L2
// wb-inv anywhere. The h ping-pong and the barrier counters are accessed
// ONLY via relaxed agent-scope atomics (-> plain global ops with sc1 that
// bypass the per-XCD L2 and are coherent at L3). Ordering producer->counter
// relies on the s_waitcnt vmcnt(0) hipcc emits before every s_barrier
// (drains the sc1 stores to L3 before tid0 passes __syncthreads and
// increments the counter). L2 stays warm with projE / x / W fragments.
// ---------------------------------------------------------------------------
__global__ __launch_bounds__(512, 2)
void rnn_persist(const int* __restrict__ x, const float* __restrict__ projE,
                 const unsigned short* __restrict__ w_hh_frag,
                 const unsigned short* __restrict__ w_hy_frag,
                 const float* __restrict__ b_y,
                 unsigned short* __restrict__ hbuf,
                 float* __restrict__ out_logits, float* __restrict__ out_final,
                 unsigned int* __restrict__ bar)
{
    const int tid  = threadIdx.x;
    const int bid  = blockIdx.x;
    const int g    = bid >> 5;        // group 0..7 (16 batch rows)
    const int cb   = bid & 31;        // col-block 0..31 (64 hidden cols)
    const int r0   = g * 16;
    const int c0   = cb * 64;

    const int w    = tid >> 6;        // wave 0..7 = K-split index
    const int lane = tid & 63;
    const int col  = lane & 15;
    const int q    = lane >> 4;
    const int am   = r0 + col;        // A-fragment row (batch index)

    const bool duty = (cb < 6);

    __shared__ f32x4 part [8][4][64]; // 32 KB h partials
    __shared__ f32x4 partL[8][64];    //  8 KB logits partials

    // ---- persistent W_hh fragments in registers (static indexing only) ----
    bf16x8 breg[4][8];
    {
        const bf16x8* Wc = (const bf16x8*)w_hh_frag;
        #pragma unroll
        for (int n = 0; n < 4; ++n) {
            const bf16x8* Bt = Wc + (size_t)(cb * 4 + n) * 4096 + lane;
            #pragma unroll
            for (int j = 0; j < 8; ++j) breg[n][j] = Bt[(w * 8 + j) * 64];
        }
    }
    bf16x8 wreg[8];
    if (duty) {
        const bf16x8* Bt = (const bf16x8*)w_hy_frag + (size_t)cb * 4096 + lane;
        #pragma unroll
        for (int j = 0; j < 8; ++j) wreg[j] = Bt[(w * 8 + j) * 64];
    }

    unsigned int* ctr = bar + g * 32;   // 128 B spacing between groups

    for (int t = 0; t < LL; ++t) {
        const unsigned short* hp = hbuf + (size_t)(t & 1) * BBHH;
        unsigned short*       hn = hbuf + (size_t)((t + 1) & 1) * BBHH;

        // A fragments via coherent (sc1) 8B atomic loads from L3
        const unsigned long long* Ap =
            (const unsigned long long*)(hp + (size_t)am * HH);
        bf16x8 a[8];
        #pragma unroll
        for (int j = 0; j < 8; ++j) {
            union { unsigned long long u[2]; bf16x8 v; } cv;
            const int base = ((w * 8 + j) * 4 + q) * 2;
            cv.u[0] = __hip_atomic_load(Ap + base,     __ATOMIC_RELAXED,
                                        __HIP_MEMORY_SCOPE_AGENT);
            cv.u[1] = __hip_atomic_load(Ap + base + 1, __ATOMIC_RELAXED,
                                        __HIP_MEMORY_SCOPE_AGENT);
            a[j] = cv.v;
        }

        f32x4 acc0 = {0.f,0.f,0.f,0.f}, acc1 = {0.f,0.f,0.f,0.f};
        f32x4 acc2 = {0.f,0.f,0.f,0.f}, acc3 = {0.f,0.f,0.f,0.f};
        f32x4 accL = {0.f,0.f,0.f,0.f};
        #pragma unroll
        for (int j = 0; j < 8; ++j) {   // 4 independent chains of 8
            acc0 = __builtin_amdgcn_mfma_f32_16x16x32_bf16(a[j], breg[0][j], acc0, 0, 0, 0);
            acc1 = __builtin_amdgcn_mfma_f32_16x16x32_bf16(a[j], breg[1][j], acc1, 0, 0, 0);
            acc2 = __builtin_amdgcn_mfma_f32_16x16x32_bf16(a[j], breg[2][j], acc2, 0, 0, 0);
            acc3 = __builtin_amdgcn_mfma_f32_16x16x32_bf16(a[j], breg[3][j], acc3, 0, 0, 0);
        }
        if (duty) {
            #pragma unroll
            for (int j = 0; j < 8; ++j)
                accL = __builtin_amdgcn_mfma_f32_16x16x32_bf16(a[j], wreg[j], accL, 0, 0, 0);
        }

        part[w][0][lane] = acc0; part[w][1][lane] = acc1;
        part[w][2][lane] = acc2; part[w][3][lane] = acc3;
        if (duty) partL[w][lane] = accL;
        __syncthreads();

        if (w < 4) {
            // reduce K-split partials for tile n=w, then epilogue
            f32x4 s = part[0][w][lane];
            #pragma unroll
            for (int k = 1; k < 8; ++k) s += part[k][w][lane];
            const int ccol = c0 + w * 16 + col;
            float hv[4];
            #pragma unroll
            for (int r = 0; r < 4; ++r) {
                const int row = r0 + q * 4 + r;
                const int tok = x[(size_t)row * LL + t];
                float v = s[r] + projE[(size_t)tok * HH + ccol];
                v = fminf(fmaxf(v, -15.f), 15.f);
                float e2 = __expf(2.f * v);
                hv[r] = (e2 - 1.f) / (e2 + 1.f);   // tanh
            }
            // pack lane pairs (cols ccol, ccol+1) into one 4B coherent store
            #pragma unroll
            for (int r = 0; r < 4; ++r) {
                float other = __shfl_xor(hv[r], 1, 64);
                if ((lane & 1) == 0) {
                    const int row = r0 + q * 4 + r;
                    unsigned int pk = (unsigned int)f2bf(hv[r])
                                    | ((unsigned int)f2bf(other) << 16);
                    __hip_atomic_store(
                        (unsigned int*)(hn + (size_t)row * HH + ccol), pk,
                        __ATOMIC_RELAXED, __HIP_MEMORY_SCOPE_AGENT);
                    if (t == LL - 1) {
                        float2 fo; fo.x = hv[r]; fo.y = other;
                        *(float2*)(out_final + (size_t)row * HH + ccol) = fo;
                    }
                }
            }
        }

        // arrive: hipcc drains vmcnt(0) before s_barrier -> all sc1 h-stores
        // of every wave are at L3 before any thread passes this barrier.
        __syncthreads();
        if (tid == 0)
            __hip_atomic_fetch_add(ctr, 1u, __ATOMIC_RELAXED,
                                   __HIP_MEMORY_SCOPE_AGENT);

        // logits for position t-1 overlap the barrier wait (normal stores;
        // their drain happens at the next s_barrier, hidden under the poll)
        if (w == 4 && duty && t > 0) {
            f32x4 s = partL[0][lane];
            #pragma unroll
            for (int k = 1; k < 8; ++k) s += partL[k][lane];
            const int lcol = cb * 16 + col;
            const float by = b_y[lcol];
            #pragma unroll
            for (int r = 0; r < 4; ++r) {
                const int row = r0 + q * 4 + r;
                out_logits[(size_t)row * (LL * VV) + (size_t)(t - 1) * VV + lcol]
                    = s[r] + by;
            }
        }

        if (tid == 0) {
            const unsigned int tgt = 32u * (unsigned int)(t + 1);
            while (__hip_atomic_load(ctr, __ATOMIC_RELAXED,
                                     __HIP_MEMORY_SCOPE_AGENT) < tgt)
                __builtin_amdgcn_s_sleep(1);
        }
        __syncthreads();
    }

    // final logits (position LL-1) from h_512, which sits in ping buffer 0
    if (duty) {
        const unsigned long long* Ap =
            (const unsigned long long*)(hbuf + (size_t)am * HH);
        bf16x8 a[8];
        #pragma unroll
        for (int j = 0; j < 8; ++j) {
            union { unsigned long long u[2]; bf16x8 v; } cv;
            const int base = ((w * 8 + j) * 4 + q) * 2;
            cv.u[0] = __hip_atomic_load(Ap + base,     __ATOMIC_RELAXED,
                                        __HIP_MEMORY_SCOPE_AGENT);
            cv.u[1] = __hip_atomic_load(Ap + base + 1, __ATOMIC_RELAXED,
                                        __HIP_MEMORY_SCOPE_AGENT);
            a[j] = cv.v;
        }
        f32x4 accL = {0.f,0.f,0.f,0.f};
        #pragma unroll
        for (int j = 0; j < 8; ++j)
            accL = __builtin_amdgcn_mfma_f32_16x16x32_bf16(a[j], wreg[j], accL, 0, 0, 0);
        partL[w][lane] = accL;
        __syncthreads();
        if (w == 4) {
            f32x4 s = partL[0][lane];
            #pragma unroll
            for (int k = 1; k < 8; ++k) s += partL[k][lane];
            const int lcol = cb * 16 + col;
            const float by = b_y[lcol];
            #pragma unroll
            for (int r = 0; r < 4; ++r) {
                const int row = r0 + q * 4 + r;
                out_logits[(size_t)row * (LL * VV) + (size_t)(LL - 1) * VV + lcol]
                    = s[r] + by;
            }
        }
    }
}

extern "C" void kernel_launch(void* const* d_in, const int* in_sizes, int n_in,
                              void* d_out, int out_size, void* d_ws, size_t ws_size,
                              hipStream_t stream) {
    const int*   x      = (const int*)  d_in[0];
    const float* hidden = (const float*)d_in[1];
    const float* emb    = (const float*)d_in[2];
    const float* W_xh   = (const float*)d_in[3];
    const float* W_hh   = (const float*)d_in[4];
    const float* b_h    = (const float*)d_in[5];
    const float* W_hy   = (const float*)d_in[6];
    const float* b_y    = (const float*)d_in[7];

    float* out_logits = (float*)d_out;                          // [B][L][V]
    float* out_final  = out_logits + (size_t)BB * LL * VV;      // [B][H]

    // workspace layout (~10.62 MB): whh_frag 8 MB | why_frag 384 KB |
    // projE 768 KB | h ping-pong 1 MB | padded barrier counters 1 KB
    char* ws = (char*)d_ws;
    unsigned short* w_hh_frag = (unsigned short*)ws;
    unsigned short* w_hy_frag = (unsigned short*)(ws + 8388608);
    float*          projE     = (float*)        (ws + 8388608 + 393216);
    unsigned short* hbuf      = (unsigned short*)(ws + 8388608 + 393216 + 786432);
    unsigned int*   bar       = (unsigned int*) (ws + 8388608 + 393216 + 786432 + 1048576);

    setup_kernel<<<dim3(1024), dim3(256), 0, stream>>>(
        x, hidden, emb, W_xh, W_hh, b_h, W_hy,
        projE, w_hh_frag, w_hy_frag, hbuf, bar);

    void* args[] = { (void*)&x, (void*)&projE, (void*)&w_hh_frag, (void*)&w_hy_frag,
                     (void*)&b_y, (void*)&hbuf, (void*)&out_logits, (void*)&out_final,
                     (void*)&bar };
    hipLaunchCooperativeKernel((void*)rnn_persist, dim3(256), dim3(512),
                               args, 0, stream);
}

// Round 3
// 3400.347 us; speedup vs baseline: 5.1431x; 1.0164x over previous
//
#include <hip/hip_runtime.h>

#define BB 128   // batch
#define LL 512   // seq len
#define HH 2048  // hidden
#define EE 128   // embed
#define VV 96    // vocab
#define BBHH (BB * HH)

typedef short bf16x8 __attribute__((ext_vector_type(8)));
typedef float f32x4 __attribute__((ext_vector_type(4)));

__device__ __forceinline__ unsigned short f2bf(float f) {
    union { float f; unsigned int u; } c; c.f = f;
    unsigned int u = c.u;
    return (unsigned short)((u + 0x7FFFu + ((u >> 16) & 1u)) >> 16);  // RNE
}

// ---------------------------------------------------------------------------
// Setup: identical packing to the proven kernel (W_hh / W_hy -> MFMA-B
// fragment-linear bf16 tiles; projE fp32; h0 -> bf16) + zero the per-
// (block,wave) flag array (8 groups x 32 blocks x 4 waves = 1024 words).
// ---------------------------------------------------------------------------
__global__ __launch_bounds__(256)
void setup_kernel(const int* __restrict__ x, const float* __restrict__ hidden,
                  const float* __restrict__ emb, const float* __restrict__ W_xh,
                  const float* __restrict__ W_hh, const float* __restrict__ b_h,
                  const float* __restrict__ W_hy,
                  float* __restrict__ projE,
                  unsigned short* __restrict__ w_hh_frag,
                  unsigned short* __restrict__ w_hy_frag,
                  unsigned short* __restrict__ hbuf,
                  unsigned int* __restrict__ bar)
{
    const int gtid = blockIdx.x * 256 + threadIdx.x;
    const int GT   = gridDim.x * 256;

    if (gtid < 1024) bar[gtid] = 0u;   // flags, reset every run

    for (int idx = gtid; idx < HH * HH; idx += GT) {
        int tile = idx >> 15;
        int rem  = idx & 32767;
        int c    = rem >> 3;
        int j    = rem & 7;
        int l    = c & 63;
        int i    = c >> 6;
        int row  = tile * 16 + (l & 15);
        int k    = i * 32 + (l >> 4) * 8 + j;
        w_hh_frag[idx] = f2bf(W_hh[(size_t)row * HH + k]);
    }
    for (int idx = gtid; idx < VV * HH; idx += GT) {
        int tile = idx >> 15;
        int rem  = idx & 32767;
        int c    = rem >> 3;
        int j    = rem & 7;
        int l    = c & 63;
        int i    = c >> 6;
        int row  = tile * 16 + (l & 15);
        int k    = i * 32 + (l >> 4) * 8 + j;
        w_hy_frag[idx] = f2bf(W_hy[(size_t)row * HH + k]);
    }
    for (int i = gtid; i < VV * HH; i += GT) {
        int v  = i >> 11;
        int hc = i & (HH - 1);
        const float4* ep = (const float4*)(emb + (size_t)v * EE);
        const float4* wp = (const float4*)(W_xh + (size_t)hc * EE);
        float s = b_h[hc];
        #pragma unroll 8
        for (int e = 0; e < EE / 4; ++e) {
            float4 a = ep[e], b = wp[e];
            s += a.x * b.x + a.y * b.y + a.z * b.z + a.w * b.w;
        }
        projE[i] = s;
    }
    for (int i = gtid; i < BBHH; i += GT) hbuf[i] = f2bf(hidden[i]);
}

// poll 16 producer-wave flags (lane i < 16 owns one) until all >= tgt.
// Branch dependence + compiler fence order the subsequent data loads;
// no HW acquire fence (would emit buffer_inv -> L2 nuke).
__device__ __forceinline__ void wait_flags(const unsigned int* fl,
                                           unsigned int tgt, int lane)
{
    if (lane < 16) {
        while (__hip_atomic_load(fl + lane, __ATOMIC_RELAXED,
                                 __HIP_MEMORY_SCOPE_AGENT) < tgt)
            __builtin_amdgcn_s_sleep(1);
    }
    asm volatile("" ::: "memory");
}

// ---------------------------------------------------------------------------
// Persistent cooperative kernel, v3. Decomposition as v2 (group g = 16 batch
// rows, 32 col-blocks x 64 cols, 8-wave K-split, W_hh in VGPRs, h ping-pong
// via relaxed agent atomics at L3). Sync redesign: the group-wide counter
// barrier is replaced by per-(block,wave) epoch flags. Producer wave w<4
// (owns 16 h-cols) drains its own sc1 stores (s_waitcnt vmcnt(0)) and
// publishes flag=t+1. Consumer wave w needs only K-range [w*256,(w+1)*256)
// = blocks 4w..4w+3 -> polls 16 flags (4 blocks x 4 waves). Fan-in 32 -> 4.
// Depth-2 ping-pong stays safe: a block writes h_{t+2} only after all its
// waves saw all 32 producers at >= t+1 (union of fan-ins) + __syncthreads,
// and flag t+1 is only set after that producer finished reading h_t.
// ---------------------------------------------------------------------------
__global__ __launch_bounds__(512, 2)
void rnn_persist(const int* __restrict__ x, const float* __restrict__ projE,
                 const unsigned short* __restrict__ w_hh_frag,
                 const unsigned short* __restrict__ w_hy_frag,
                 const float* __restrict__ b_y,
                 unsigned short* __restrict__ hbuf,
                 float* __restrict__ out_logits, float* __restrict__ out_final,
                 unsigned int* __restrict__ bar)
{
    const int tid  = threadIdx.x;
    const int bid  = blockIdx.x;
    const int g    = bid >> 5;        // group 0..7 (16 batch rows)
    const int cb   = bid & 31;        // col-block 0..31 (64 hidden cols)
    const int r0   = g * 16;
    const int c0   = cb * 64;

    const int w    = tid >> 6;        // wave 0..7 = K-split index
    const int lane = tid & 63;
    const int col  = lane & 15;
    const int q    = lane >> 4;
    const int am   = r0 + col;        // A-fragment row (batch index)

    const bool duty = (cb < 6);

    __shared__ f32x4 part [8][4][64]; // 32 KB h partials
    __shared__ f32x4 partL[8][64];    //  8 KB logits partials

    // ---- persistent W_hh fragments in registers (static indexing only) ----
    bf16x8 breg[4][8];
    {
        const bf16x8* Wc = (const bf16x8*)w_hh_frag;
        #pragma unroll
        for (int n = 0; n < 4; ++n) {
            const bf16x8* Bt = Wc + (size_t)(cb * 4 + n) * 4096 + lane;
            #pragma unroll
            for (int j = 0; j < 8; ++j) breg[n][j] = Bt[(w * 8 + j) * 64];
        }
    }
    bf16x8 wreg[8];
    if (duty) {
        const bf16x8* Bt = (const bf16x8*)w_hy_frag + (size_t)cb * 4096 + lane;
        #pragma unroll
        for (int j = 0; j < 8; ++j) wreg[j] = Bt[(w * 8 + j) * 64];
    }

    // consumer: 16 flag words for this wave's 4 producer blocks
    const unsigned int* flr = bar + g * 128 + w * 16;
    // producer: this block's flag word for wave w (w<4)
    unsigned int* flw = bar + (g * 32 + cb) * 4 + w;

    for (int t = 0; t < LL; ++t) {
        const unsigned short* hp = hbuf + (size_t)(t & 1) * BBHH;
        unsigned short*       hn = hbuf + (size_t)((t + 1) & 1) * BBHH;

        // ---- epilogue operand prefetch (independent of h_t) ----
        int   tokp[4];
        float pEp[4];
        const int ccol = c0 + w * 16 + col;
        if (w < 4) {
            #pragma unroll
            for (int r = 0; r < 4; ++r) {
                const int row = r0 + q * 4 + r;
                tokp[r] = x[(size_t)row * LL + t];
            }
            #pragma unroll
            for (int r = 0; r < 4; ++r)
                pEp[r] = projE[(size_t)tokp[r] * HH + ccol];
        }

        // ---- wait for this wave's 4 producer blocks (fan-in 4) ----
        wait_flags(flr, (unsigned int)t, lane);

        // ---- A fragments via coherent (sc1) 8B atomic loads from L3 ----
        const unsigned long long* Ap =
            (const unsigned long long*)(hp + (size_t)am * HH);
        bf16x8 a[8];
        #pragma unroll
        for (int j = 0; j < 8; ++j) {
            union { unsigned long long u[2]; bf16x8 v; } cv;
            const int base = ((w * 8 + j) * 4 + q) * 2;
            cv.u[0] = __hip_atomic_load(Ap + base,     __ATOMIC_RELAXED,
                                        __HIP_MEMORY_SCOPE_AGENT);
            cv.u[1] = __hip_atomic_load(Ap + base + 1, __ATOMIC_RELAXED,
                                        __HIP_MEMORY_SCOPE_AGENT);
            a[j] = cv.v;
        }

        f32x4 acc0 = {0.f,0.f,0.f,0.f}, acc1 = {0.f,0.f,0.f,0.f};
        f32x4 acc2 = {0.f,0.f,0.f,0.f}, acc3 = {0.f,0.f,0.f,0.f};
        f32x4 accL = {0.f,0.f,0.f,0.f};
        #pragma unroll
        for (int j = 0; j < 8; ++j) {   // 4 independent chains of 8
            acc0 = __builtin_amdgcn_mfma_f32_16x16x32_bf16(a[j], breg[0][j], acc0, 0, 0, 0);
            acc1 = __builtin_amdgcn_mfma_f32_16x16x32_bf16(a[j], breg[1][j], acc1, 0, 0, 0);
            acc2 = __builtin_amdgcn_mfma_f32_16x16x32_bf16(a[j], breg[2][j], acc2, 0, 0, 0);
            acc3 = __builtin_amdgcn_mfma_f32_16x16x32_bf16(a[j], breg[3][j], acc3, 0, 0, 0);
        }
        if (duty) {
            #pragma unroll
            for (int j = 0; j < 8; ++j)
                accL = __builtin_amdgcn_mfma_f32_16x16x32_bf16(a[j], wreg[j], accL, 0, 0, 0);
        }

        part[w][0][lane] = acc0; part[w][1][lane] = acc1;
        part[w][2][lane] = acc2; part[w][3][lane] = acc3;
        if (duty) partL[w][lane] = accL;
        __syncthreads();

        if (w < 4) {
            // reduce K-split partials for tile n=w, then epilogue
            f32x4 s = part[0][w][lane];
            #pragma unroll
            for (int k = 1; k < 8; ++k) s += part[k][w][lane];
            float hv[4];
            #pragma unroll
            for (int r = 0; r < 4; ++r) {
                float v = s[r] + pEp[r];
                v = fminf(fmaxf(v, -15.f), 15.f);
                float e2 = __expf(2.f * v);
                hv[r] = (e2 - 1.f) / (e2 + 1.f);   // tanh
            }
            // pack lane pairs (cols ccol, ccol+1) into one 4B coherent store
            #pragma unroll
            for (int r = 0; r < 4; ++r) {
                float other = __shfl_xor(hv[r], 1, 64);
                if ((lane & 1) == 0) {
                    const int row = r0 + q * 4 + r;
                    unsigned int pk = (unsigned int)f2bf(hv[r])
                                    | ((unsigned int)f2bf(other) << 16);
                    __hip_atomic_store(
                        (unsigned int*)(hn + (size_t)row * HH + ccol), pk,
                        __ATOMIC_RELAXED, __HIP_MEMORY_SCOPE_AGENT);
                    if (t == LL - 1) {
                        float2 fo; fo.x = hv[r]; fo.y = other;
                        *(float2*)(out_final + (size_t)row * HH + ccol) = fo;
                    }
                }
            }
            // publish: my 16 h-cols for step t+1 are at L3
            asm volatile("s_waitcnt vmcnt(0)" ::: "memory");
            if (lane == 0)
                __hip_atomic_store(flw, (unsigned int)(t + 1),
                                   __ATOMIC_RELAXED, __HIP_MEMORY_SCOPE_AGENT);
        } else if (w == 4 && duty && t > 0) {
            // logits for position t-1 (normal stores, host-visible at exit)
            f32x4 s = partL[0][lane];
            #pragma unroll
            for (int k = 1; k < 8; ++k) s += partL[k][lane];
            const int lcol = cb * 16 + col;
            const float by = b_y[lcol];
            #pragma unroll
            for (int r = 0; r < 4; ++r) {
                const int row = r0 + q * 4 + r;
                out_logits[(size_t)row * (LL * VV) + (size_t)(t - 1) * VV + lcol]
                    = s[r] + by;
            }
        }

        __syncthreads();   // protect part[] WAR for next iteration
    }

    // final logits (position LL-1) from h_512, which sits in ping buffer 0
    if (duty) {
        wait_flags(flr, (unsigned int)LL, lane);   // producers' step-511 done
        const unsigned long long* Ap =
            (const unsigned long long*)(hbuf + (size_t)am * HH);
        bf16x8 a[8];
        #pragma unroll
        for (int j = 0; j < 8; ++j) {
            union { unsigned long long u[2]; bf16x8 v; } cv;
            const int base = ((w * 8 + j) * 4 + q) * 2;
            cv.u[0] = __hip_atomic_load(Ap + base,     __ATOMIC_RELAXED,
                                        __HIP_MEMORY_SCOPE_AGENT);
            cv.u[1] = __hip_atomic_load(Ap + base + 1, __ATOMIC_RELAXED,
                                        __HIP_MEMORY_SCOPE_AGENT);
            a[j] = cv.v;
        }
        f32x4 accL = {0.f,0.f,0.f,0.f};
        #pragma unroll
        for (int j = 0; j < 8; ++j)
            accL = __builtin_amdgcn_mfma_f32_16x16x32_bf16(a[j], wreg[j], accL, 0, 0, 0);
        partL[w][lane] = accL;
        __syncthreads();
        if (w == 4) {
            f32x4 s = partL[0][lane];
            #pragma unroll
            for (int k = 1; k < 8; ++k) s += partL[k][lane];
            const int lcol = cb * 16 + col;
            const float by = b_y[lcol];
            #pragma unroll
            for (int r = 0; r < 4; ++r) {
                const int row = r0 + q * 4 + r;
                out_logits[(size_t)row * (LL * VV) + (size_t)(LL - 1) * VV + lcol]
                    = s[r] + by;
            }
        }
    }
}

extern "C" void kernel_launch(void* const* d_in, const int* in_sizes, int n_in,
                              void* d_out, int out_size, void* d_ws, size_t ws_size,
                              hipStream_t stream) {
    const int*   x      = (const int*)  d_in[0];
    const float* hidden = (const float*)d_in[1];
    const float* emb    = (const float*)d_in[2];
    const float* W_xh   = (const float*)d_in[3];
    const float* W_hh   = (const float*)d_in[4];
    const float* b_h    = (const float*)d_in[5];
    const float* W_hy   = (const float*)d_in[6];
    const float* b_y    = (const float*)d_in[7];

    float* out_logits = (float*)d_out;                          // [B][L][V]
    float* out_final  = out_logits + (size_t)BB * LL * VV;      // [B][H]

    // workspace layout (~10.62 MB): whh_frag 8 MB | why_frag 384 KB |
    // projE 768 KB | h ping-pong 1 MB | flags 4 KB
    char* ws = (char*)d_ws;
    unsigned short* w_hh_frag = (unsigned short*)ws;
    unsigned short* w_hy_frag = (unsigned short*)(ws + 8388608);
    float*          projE     = (float*)        (ws + 8388608 + 393216);
    unsigned short* hbuf      = (unsigned short*)(ws + 8388608 + 393216 + 786432);
    unsigned int*   bar       = (unsigned int*) (ws + 8388608 + 393216 + 786432 + 1048576);

    setup_kernel<<<dim3(1024), dim3(256), 0, stream>>>(
        x, hidden, emb, W_xh, W_hh, b_h, W_hy,
        projE, w_hh_frag, w_hy_frag, hbuf, bar);

    void* args[] = { (void*)&x, (void*)&projE, (void*)&w_hh_frag, (void*)&w_hy_frag,
                     (void*)&b_y, (void*)&hbuf, (void*)&out_logits, (void*)&out_final,
                     (void*)&bar };
    hipLaunchCooperativeKernel((void*)rnn_persist, dim3(256), dim3(512),
                               args, 0, stream);
}

// Round 7
// 3092.681 us; speedup vs baseline: 5.6547x; 1.0995x over previous
//
#include <hip/hip_runtime.h>

#define BB 128   // batch
#define LL 512   // seq len
#define HH 2048  // hidden
#define EE 128   // embed
#define VV 96    // vocab
#define BBHH (BB * HH)

// flag spreading: one flag per 128B line (32 words)
#define FSTRIDE 32

typedef short bf16x8 __attribute__((ext_vector_type(8)));
typedef float f32x4 __attribute__((ext_vector_type(4)));

__device__ __forceinline__ unsigned short f2bf(float f) {
    union { float f; unsigned int u; } c; c.f = f;
    unsigned int u = c.u;
    return (unsigned short)((u + 0x7FFFu + ((u >> 16) & 1u)) >> 16);  // RNE
}

// ---------------------------------------------------------------------------
// Setup: identical packing to the proven kernel (W_hh / W_hy -> MFMA-B
// fragment-linear bf16 tiles; projE fp32; h0 -> bf16) + zero the spread
// flag array (1024 flags x 32-word stride = 32768 words = 128 KB).
// ---------------------------------------------------------------------------
__global__ __launch_bounds__(256)
void setup_kernel(const int* __restrict__ x, const float* __restrict__ hidden,
                  const float* __restrict__ emb, const float* __restrict__ W_xh,
                  const float* __restrict__ W_hh, const float* __restrict__ b_h,
                  const float* __restrict__ W_hy,
                  float* __restrict__ projE,
                  unsigned short* __restrict__ w_hh_frag,
                  unsigned short* __restrict__ w_hy_frag,
                  unsigned short* __restrict__ hbuf,
                  unsigned int* __restrict__ bar)
{
    const int gtid = blockIdx.x * 256 + threadIdx.x;
    const int GT   = gridDim.x * 256;

    if (gtid < 1024 * FSTRIDE) bar[gtid] = 0u;   // flags, reset every run

    for (int idx = gtid; idx < HH * HH; idx += GT) {
        int tile = idx >> 15;
        int rem  = idx & 32767;
        int c    = rem >> 3;
        int j    = rem & 7;
        int l    = c & 63;
        int i    = c >> 6;
        int row  = tile * 16 + (l & 15);
        int k    = i * 32 + (l >> 4) * 8 + j;
        w_hh_frag[idx] = f2bf(W_hh[(size_t)row * HH + k]);
    }
    for (int idx = gtid; idx < VV * HH; idx += GT) {
        int tile = idx >> 15;
        int rem  = idx & 32767;
        int c    = rem >> 3;
        int j    = rem & 7;
        int l    = c & 63;
        int i    = c >> 6;
        int row  = tile * 16 + (l & 15);
        int k    = i * 32 + (l >> 4) * 8 + j;
        w_hy_frag[idx] = f2bf(W_hy[(size_t)row * HH + k]);
    }
    for (int i = gtid; i < VV * HH; i += GT) {
        int v  = i >> 11;
        int hc = i & (HH - 1);
        const float4* ep = (const float4*)(emb + (size_t)v * EE);
        const float4* wp = (const float4*)(W_xh + (size_t)hc * EE);
        float s = b_h[hc];
        #pragma unroll 8
        for (int e = 0; e < EE / 4; ++e) {
            float4 a = ep[e], b = wp[e];
            s += a.x * b.x + a.y * b.y + a.z * b.z + a.w * b.w;
        }
        projE[i] = s;
    }
    for (int i = gtid; i < BBHH; i += GT) hbuf[i] = f2bf(hidden[i]);
}

// poll 16 producer-wave flags (lane i < 16 owns one, each on its own 128B
// line) until all >= tgt. Branch dependence + compiler fence order the
// subsequent data loads; no HW acquire fence (would emit buffer_inv).
__device__ __forceinline__ void wait_flags(const unsigned int* fl,
                                           unsigned int tgt, int lane)
{
    if (lane < 16) {
        while (__hip_atomic_load(fl + lane * FSTRIDE, __ATOMIC_RELAXED,
                                 __HIP_MEMORY_SCOPE_AGENT) < tgt)
            __builtin_amdgcn_s_sleep(1);
    }
    asm volatile("" ::: "memory");
}

// ---------------------------------------------------------------------------
// Persistent cooperative kernel, v3 + flag spreading. Decomposition as v2
// (group g = 16 batch rows, 32 col-blocks x 64 cols, 8-wave K-split, W_hh in
// VGPRs, h ping-pong via relaxed agent atomics at L3). Sync: per-(block,wave)
// epoch flags, each flag on its own 128B line to kill L3 same-line
// serialization among ~512 pollers (the round-2/3 latency theory).
// Producer wave w<4 drains its sc1 stores (s_waitcnt vmcnt(0)) and publishes
// flag=t+1. Consumer wave w polls 16 flags (its 4 producer blocks x 4 waves).
// Depth-2 ping-pong safety: a block writes h_{t+2} only after all its waves
// saw all 32 producers at >= t+1 (union of fan-ins) + __syncthreads, and
// flag t+1 is only set after that producer finished reading h_t.
// ---------------------------------------------------------------------------
__global__ __launch_bounds__(512, 2)
void rnn_persist(const int* __restrict__ x, const float* __restrict__ projE,
                 const unsigned short* __restrict__ w_hh_frag,
                 const unsigned short* __restrict__ w_hy_frag,
                 const float* __restrict__ b_y,
                 unsigned short* __restrict__ hbuf,
                 float* __restrict__ out_logits, float* __restrict__ out_final,
                 unsigned int* __restrict__ bar)
{
    const int tid  = threadIdx.x;
    const int bid  = blockIdx.x;
    const int g    = bid >> 5;        // group 0..7 (16 batch rows)
    const int cb   = bid & 31;        // col-block 0..31 (64 hidden cols)
    const int r0   = g * 16;
    const int c0   = cb * 64;

    const int w    = tid >> 6;        // wave 0..7 = K-split index
    const int lane = tid & 63;
    const int col  = lane & 15;
    const int q    = lane >> 4;
    const int am   = r0 + col;        // A-fragment row (batch index)

    const bool duty = (cb < 6);

    __shared__ f32x4 part [8][4][64]; // 32 KB h partials
    __shared__ f32x4 partL[8][64];    //  8 KB logits partials

    // ---- persistent W_hh fragments in registers (static indexing only) ----
    bf16x8 breg[4][8];
    {
        const bf16x8* Wc = (const bf16x8*)w_hh_frag;
        #pragma unroll
        for (int n = 0; n < 4; ++n) {
            const bf16x8* Bt = Wc + (size_t)(cb * 4 + n) * 4096 + lane;
            #pragma unroll
            for (int j = 0; j < 8; ++j) breg[n][j] = Bt[(w * 8 + j) * 64];
        }
    }
    bf16x8 wreg[8];
    if (duty) {
        const bf16x8* Bt = (const bf16x8*)w_hy_frag + (size_t)cb * 4096 + lane;
        #pragma unroll
        for (int j = 0; j < 8; ++j) wreg[j] = Bt[(w * 8 + j) * 64];
    }

    // consumer: 16 flag lines for this wave's 4 producer blocks
    const unsigned int* flr = bar + (size_t)(g * 128 + w * 16) * FSTRIDE;
    // producer: this block's flag line for wave w (w<4)
    unsigned int* flw = bar + (size_t)((g * 32 + cb) * 4 + w) * FSTRIDE;

    for (int t = 0; t < LL; ++t) {
        const unsigned short* hp = hbuf + (size_t)(t & 1) * BBHH;
        unsigned short*       hn = hbuf + (size_t)((t + 1) & 1) * BBHH;

        // ---- epilogue operand prefetch (independent of h_t) ----
        int   tokp[4];
        float pEp[4];
        const int ccol = c0 + w * 16 + col;
        if (w < 4) {
            #pragma unroll
            for (int r = 0; r < 4; ++r) {
                const int row = r0 + q * 4 + r;
                tokp[r] = x[(size_t)row * LL + t];
            }
            #pragma unroll
            for (int r = 0; r < 4; ++r)
                pEp[r] = projE[(size_t)tokp[r] * HH + ccol];
        }

        // ---- wait for this wave's 4 producer blocks (fan-in 4) ----
        wait_flags(flr, (unsigned int)t, lane);

        // ---- A fragments via coherent (sc1) 8B atomic loads from L3 ----
        const unsigned long long* Ap =
            (const unsigned long long*)(hp + (size_t)am * HH);
        bf16x8 a[8];
        #pragma unroll
        for (int j = 0; j < 8; ++j) {
            union { unsigned long long u[2]; bf16x8 v; } cv;
            const int base = ((w * 8 + j) * 4 + q) * 2;
            cv.u[0] = __hip_atomic_load(Ap + base,     __ATOMIC_RELAXED,
                                        __HIP_MEMORY_SCOPE_AGENT);
            cv.u[1] = __hip_atomic_load(Ap + base + 1, __ATOMIC_RELAXED,
                                        __HIP_MEMORY_SCOPE_AGENT);
            a[j] = cv.v;
        }

        f32x4 acc0 = {0.f,0.f,0.f,0.f}, acc1 = {0.f,0.f,0.f,0.f};
        f32x4 acc2 = {0.f,0.f,0.f,0.f}, acc3 = {0.f,0.f,0.f,0.f};
        f32x4 accL = {0.f,0.f,0.f,0.f};
        #pragma unroll
        for (int j = 0; j < 8; ++j) {   // 4 independent chains of 8
            acc0 = __builtin_amdgcn_mfma_f32_16x16x32_bf16(a[j], breg[0][j], acc0, 0, 0, 0);
            acc1 = __builtin_amdgcn_mfma_f32_16x16x32_bf16(a[j], breg[1][j], acc1, 0, 0, 0);
            acc2 = __builtin_amdgcn_mfma_f32_16x16x32_bf16(a[j], breg[2][j], acc2, 0, 0, 0);
            acc3 = __builtin_amdgcn_mfma_f32_16x16x32_bf16(a[j], breg[3][j], acc3, 0, 0, 0);
        }
        if (duty) {
            #pragma unroll
            for (int j = 0; j < 8; ++j)
                accL = __builtin_amdgcn_mfma_f32_16x16x32_bf16(a[j], wreg[j], accL, 0, 0, 0);
        }

        part[w][0][lane] = acc0; part[w][1][lane] = acc1;
        part[w][2][lane] = acc2; part[w][3][lane] = acc3;
        if (duty) partL[w][lane] = accL;
        __syncthreads();

        if (w < 4) {
            // reduce K-split partials for tile n=w, then epilogue
            f32x4 s = part[0][w][lane];
            #pragma unroll
            for (int k = 1; k < 8; ++k) s += part[k][w][lane];
            float hv[4];
            #pragma unroll
            for (int r = 0; r < 4; ++r) {
                float v = s[r] + pEp[r];
                v = fminf(fmaxf(v, -15.f), 15.f);
                float e2 = __expf(2.f * v);
                hv[r] = (e2 - 1.f) / (e2 + 1.f);   // tanh
            }
            // pack lane pairs (cols ccol, ccol+1) into one 4B coherent store
            #pragma unroll
            for (int r = 0; r < 4; ++r) {
                float other = __shfl_xor(hv[r], 1, 64);
                if ((lane & 1) == 0) {
                    const int row = r0 + q * 4 + r;
                    unsigned int pk = (unsigned int)f2bf(hv[r])
                                    | ((unsigned int)f2bf(other) << 16);
                    __hip_atomic_store(
                        (unsigned int*)(hn + (size_t)row * HH + ccol), pk,
                        __ATOMIC_RELAXED, __HIP_MEMORY_SCOPE_AGENT);
                    if (t == LL - 1) {
                        float2 fo; fo.x = hv[r]; fo.y = other;
                        *(float2*)(out_final + (size_t)row * HH + ccol) = fo;
                    }
                }
            }
            // publish: my 16 h-cols for step t+1 are at L3
            asm volatile("s_waitcnt vmcnt(0)" ::: "memory");
            if (lane == 0)
                __hip_atomic_store(flw, (unsigned int)(t + 1),
                                   __ATOMIC_RELAXED, __HIP_MEMORY_SCOPE_AGENT);
        } else if (w == 4 && duty && t > 0) {
            // logits for position t-1 (normal stores, host-visible at exit)
            f32x4 s = partL[0][lane];
            #pragma unroll
            for (int k = 1; k < 8; ++k) s += partL[k][lane];
            const int lcol = cb * 16 + col;
            const float by = b_y[lcol];
            #pragma unroll
            for (int r = 0; r < 4; ++r) {
                const int row = r0 + q * 4 + r;
                out_logits[(size_t)row * (LL * VV) + (size_t)(t - 1) * VV + lcol]
                    = s[r] + by;
            }
        }

        __syncthreads();   // protect part[] WAR for next iteration
    }

    // final logits (position LL-1) from h_512, which sits in ping buffer 0
    if (duty) {
        wait_flags(flr, (unsigned int)LL, lane);   // producers' step-511 done
        const unsigned long long* Ap =
            (const unsigned long long*)(hbuf + (size_t)am * HH);
        bf16x8 a[8];
        #pragma unroll
        for (int j = 0; j < 8; ++j) {
            union { unsigned long long u[2]; bf16x8 v; } cv;
            const int base = ((w * 8 + j) * 4 + q) * 2;
            cv.u[0] = __hip_atomic_load(Ap + base,     __ATOMIC_RELAXED,
                                        __HIP_MEMORY_SCOPE_AGENT);
            cv.u[1] = __hip_atomic_load(Ap + base + 1, __ATOMIC_RELAXED,
                                        __HIP_MEMORY_SCOPE_AGENT);
            a[j] = cv.v;
        }
        f32x4 accL = {0.f,0.f,0.f,0.f};
        #pragma unroll
        for (int j = 0; j < 8; ++j)
            accL = __builtin_amdgcn_mfma_f32_16x16x32_bf16(a[j], wreg[j], accL, 0, 0, 0);
        partL[w][lane] = accL;
        __syncthreads();
        if (w == 4) {
            f32x4 s = partL[0][lane];
            #pragma unroll
            for (int k = 1; k < 8; ++k) s += partL[k][lane];
            const int lcol = cb * 16 + col;
            const float by = b_y[lcol];
            #pragma unroll
            for (int r = 0; r < 4; ++r) {
                const int row = r0 + q * 4 + r;
                out_logits[(size_t)row * (LL * VV) + (size_t)(LL - 1) * VV + lcol]
                    = s[r] + by;
            }
        }
    }
}

extern "C" void kernel_launch(void* const* d_in, const int* in_sizes, int n_in,
                              void* d_out, int out_size, void* d_ws, size_t ws_size,
                              hipStream_t stream) {
    const int*   x      = (const int*)  d_in[0];
    const float* hidden = (const float*)d_in[1];
    const float* emb    = (const float*)d_in[2];
    const float* W_xh   = (const float*)d_in[3];
    const float* W_hh   = (const float*)d_in[4];
    const float* b_h    = (const float*)d_in[5];
    const float* W_hy   = (const float*)d_in[6];
    const float* b_y    = (const float*)d_in[7];

    float* out_logits = (float*)d_out;                          // [B][L][V]
    float* out_final  = out_logits + (size_t)BB * LL * VV;      // [B][H]

    // workspace (~10.75 MB): whh_frag 8 MB | why_frag 384 KB | projE 768 KB |
    // h ping-pong 1 MB | spread flags 128 KB
    char* ws = (char*)d_ws;
    unsigned short* w_hh_frag = (unsigned short*)ws;
    unsigned short* w_hy_frag = (unsigned short*)(ws + 8388608);
    float*          projE     = (float*)        (ws + 8388608 + 393216);
    unsigned short* hbuf      = (unsigned short*)(ws + 8388608 + 393216 + 786432);
    unsigned int*   bar       = (unsigned int*) (ws + 8388608 + 393216 + 786432 + 1048576);

    setup_kernel<<<dim3(1024), dim3(256), 0, stream>>>(
        x, hidden, emb, W_xh, W_hh, b_h, W_hy,
        projE, w_hh_frag, w_hy_frag, hbuf, bar);

    void* args[] = { (void*)&x, (void*)&projE, (void*)&w_hh_frag, (void*)&w_hy_frag,
                     (void*)&b_y, (void*)&hbuf, (void*)&out_logits, (void*)&out_final,
                     (void*)&bar };
    hipLaunchCooperativeKernel((void*)rnn_persist, dim3(256), dim3(512),
                               args, 0, stream);
}

// Round 8
// 2999.306 us; speedup vs baseline: 5.8308x; 1.0311x over previous
//
#include <hip/hip_runtime.h>

#define BB 128   // batch
#define LL 512   // seq len
#define HH 2048  // hidden
#define EE 128   // embed
#define VV 96    // vocab
#define BBHH (BB * HH)

// flag spreading: one flag per 128B line (32 words)
#define FSTRIDE 32

typedef short bf16x8 __attribute__((ext_vector_type(8)));
typedef float f32x4 __attribute__((ext_vector_type(4)));

__device__ __forceinline__ unsigned short f2bf(float f) {
    union { float f; unsigned int u; } c; c.f = f;
    unsigned int u = c.u;
    return (unsigned short)((u + 0x7FFFu + ((u >> 16) & 1u)) >> 16);  // RNE
}

// ---------------------------------------------------------------------------
// Setup: identical packing to the proven kernel (W_hh / W_hy -> MFMA-B
// fragment-linear bf16 tiles; projE fp32; h0 -> bf16) + zero the spread
// per-BLOCK flag array (256 flags x 32-word stride = 8192 words = 32 KB).
// ---------------------------------------------------------------------------
__global__ __launch_bounds__(256)
void setup_kernel(const int* __restrict__ x, const float* __restrict__ hidden,
                  const float* __restrict__ emb, const float* __restrict__ W_xh,
                  const float* __restrict__ W_hh, const float* __restrict__ b_h,
                  const float* __restrict__ W_hy,
                  float* __restrict__ projE,
                  unsigned short* __restrict__ w_hh_frag,
                  unsigned short* __restrict__ w_hy_frag,
                  unsigned short* __restrict__ hbuf,
                  unsigned int* __restrict__ bar)
{
    const int gtid = blockIdx.x * 256 + threadIdx.x;
    const int GT   = gridDim.x * 256;

    if (gtid < 256 * FSTRIDE) bar[gtid] = 0u;   // flags, reset every run

    for (int idx = gtid; idx < HH * HH; idx += GT) {
        int tile = idx >> 15;
        int rem  = idx & 32767;
        int c    = rem >> 3;
        int j    = rem & 7;
        int l    = c & 63;
        int i    = c >> 6;
        int row  = tile * 16 + (l & 15);
        int k    = i * 32 + (l >> 4) * 8 + j;
        w_hh_frag[idx] = f2bf(W_hh[(size_t)row * HH + k]);
    }
    for (int idx = gtid; idx < VV * HH; idx += GT) {
        int tile = idx >> 15;
        int rem  = idx & 32767;
        int c    = rem >> 3;
        int j    = rem & 7;
        int l    = c & 63;
        int i    = c >> 6;
        int row  = tile * 16 + (l & 15);
        int k    = i * 32 + (l >> 4) * 8 + j;
        w_hy_frag[idx] = f2bf(W_hy[(size_t)row * HH + k]);
    }
    for (int i = gtid; i < VV * HH; i += GT) {
        int v  = i >> 11;
        int hc = i & (HH - 1);
        const float4* ep = (const float4*)(emb + (size_t)v * EE);
        const float4* wp = (const float4*)(W_xh + (size_t)hc * EE);
        float s = b_h[hc];
        #pragma unroll 8
        for (int e = 0; e < EE / 4; ++e) {
            float4 a = ep[e], b = wp[e];
            s += a.x * b.x + a.y * b.y + a.z * b.z + a.w * b.w;
        }
        projE[i] = s;
    }
    for (int i = gtid; i < BBHH; i += GT) hbuf[i] = f2bf(hidden[i]);
}

// poll 4 producer-BLOCK flags (lane i < 4 owns one, each on its own 128B
// line) until all >= tgt. Branch dependence + compiler fence order the
// subsequent data loads; no HW acquire fence (would emit buffer_inv).
__device__ __forceinline__ void wait_flags(const unsigned int* fl,
                                           unsigned int tgt, int lane)
{
    if (lane < 4) {
        while (__hip_atomic_load(fl + lane * FSTRIDE, __ATOMIC_RELAXED,
                                 __HIP_MEMORY_SCOPE_AGENT) < tgt)
            __builtin_amdgcn_s_sleep(1);
    }
    asm volatile("" ::: "memory");
}

// ---------------------------------------------------------------------------
// Persistent cooperative kernel, v5 = round-7 + per-BLOCK flags.
// Decomposition unchanged (group g = 16 batch rows, 32 col-blocks x 64 cols,
// 8-wave K-split, W_hh in VGPRs, h ping-pong via relaxed agent atomics).
// Sync: ONE epoch flag per producer block, published by the LAST of its 4
// reducer waves (LDS atomicAdd join, off-fabric). Consumer wave w polls only
// 4 flags (blocks 4w..4w+3 of its group). Cuts fabric poll streams 4x
// (128 -> 32 per block) and publish stores 4x; message congestion at the
// coherence point was the round-7 residual theory.
// Safety (same as round 3/7): block flag = t implies its 4 reducer waves
// passed step t-1's first __syncthreads (joining all 8 waves' A-reads of
// h_{t-2}) AND each drained its own h-stores (vmcnt(0)) before the LDS add;
// the 4th add's return orders the flag store after all of them. Consumer
// union over its 8 waves covers all 32 producer blocks before any h_{t+1}
// write (first __syncthreads of the next step).
// ---------------------------------------------------------------------------
__global__ __launch_bounds__(512, 2)
void rnn_persist(const int* __restrict__ x, const float* __restrict__ projE,
                 const unsigned short* __restrict__ w_hh_frag,
                 const unsigned short* __restrict__ w_hy_frag,
                 const float* __restrict__ b_y,
                 unsigned short* __restrict__ hbuf,
                 float* __restrict__ out_logits, float* __restrict__ out_final,
                 unsigned int* __restrict__ bar)
{
    const int tid  = threadIdx.x;
    const int bid  = blockIdx.x;
    const int g    = bid >> 5;        // group 0..7 (16 batch rows)
    const int cb   = bid & 31;        // col-block 0..31 (64 hidden cols)
    const int r0   = g * 16;
    const int c0   = cb * 64;

    const int w    = tid >> 6;        // wave 0..7 = K-split index
    const int lane = tid & 63;
    const int col  = lane & 15;
    const int q    = lane >> 4;
    const int am   = r0 + col;        // A-fragment row (batch index)

    const bool duty = (cb < 6);

    __shared__ f32x4 part [8][4][64]; // 32 KB h partials
    __shared__ f32x4 partL[8][64];    //  8 KB logits partials
    __shared__ unsigned int pcnt;     // producer-wave join counter (monotonic)

    // ---- persistent W_hh fragments in registers (static indexing only) ----
    bf16x8 breg[4][8];
    {
        const bf16x8* Wc = (const bf16x8*)w_hh_frag;
        #pragma unroll
        for (int n = 0; n < 4; ++n) {
            const bf16x8* Bt = Wc + (size_t)(cb * 4 + n) * 4096 + lane;
            #pragma unroll
            for (int j = 0; j < 8; ++j) breg[n][j] = Bt[(w * 8 + j) * 64];
        }
    }
    bf16x8 wreg[8];
    if (duty) {
        const bf16x8* Bt = (const bf16x8*)w_hy_frag + (size_t)cb * 4096 + lane;
        #pragma unroll
        for (int j = 0; j < 8; ++j) wreg[j] = Bt[(w * 8 + j) * 64];
    }

    if (tid == 0) pcnt = 0u;
    __syncthreads();

    // consumer: 4 per-block flag lines (producer blocks 4w..4w+3 of group g)
    const unsigned int* flr = bar + (size_t)(g * 32 + 4 * w) * FSTRIDE;
    // producer: this block's single flag line
    unsigned int* flw = bar + (size_t)(g * 32 + cb) * FSTRIDE;

    for (int t = 0; t < LL; ++t) {
        const unsigned short* hp = hbuf + (size_t)(t & 1) * BBHH;
        unsigned short*       hn = hbuf + (size_t)((t + 1) & 1) * BBHH;

        // ---- epilogue operand prefetch (independent of h_t) ----
        int   tokp[4];
        float pEp[4];
        const int ccol = c0 + w * 16 + col;
        if (w < 4) {
            #pragma unroll
            for (int r = 0; r < 4; ++r) {
                const int row = r0 + q * 4 + r;
                tokp[r] = x[(size_t)row * LL + t];
            }
            #pragma unroll
            for (int r = 0; r < 4; ++r)
                pEp[r] = projE[(size_t)tokp[r] * HH + ccol];
        }

        // ---- wait for this wave's 4 producer blocks (fan-in 4) ----
        wait_flags(flr, (unsigned int)t, lane);

        // ---- A fragments via coherent (sc1) 8B atomic loads from L3 ----
        const unsigned long long* Ap =
            (const unsigned long long*)(hp + (size_t)am * HH);
        bf16x8 a[8];
        #pragma unroll
        for (int j = 0; j < 8; ++j) {
            union { unsigned long long u[2]; bf16x8 v; } cv;
            const int base = ((w * 8 + j) * 4 + q) * 2;
            cv.u[0] = __hip_atomic_load(Ap + base,     __ATOMIC_RELAXED,
                                        __HIP_MEMORY_SCOPE_AGENT);
            cv.u[1] = __hip_atomic_load(Ap + base + 1, __ATOMIC_RELAXED,
                                        __HIP_MEMORY_SCOPE_AGENT);
            a[j] = cv.v;
        }

        f32x4 acc0 = {0.f,0.f,0.f,0.f}, acc1 = {0.f,0.f,0.f,0.f};
        f32x4 acc2 = {0.f,0.f,0.f,0.f}, acc3 = {0.f,0.f,0.f,0.f};
        f32x4 accL = {0.f,0.f,0.f,0.f};
        #pragma unroll
        for (int j = 0; j < 8; ++j) {   // 4 independent chains of 8
            acc0 = __builtin_amdgcn_mfma_f32_16x16x32_bf16(a[j], breg[0][j], acc0, 0, 0, 0);
            acc1 = __builtin_amdgcn_mfma_f32_16x16x32_bf16(a[j], breg[1][j], acc1, 0, 0, 0);
            acc2 = __builtin_amdgcn_mfma_f32_16x16x32_bf16(a[j], breg[2][j], acc2, 0, 0, 0);
            acc3 = __builtin_amdgcn_mfma_f32_16x16x32_bf16(a[j], breg[3][j], acc3, 0, 0, 0);
        }
        if (duty) {
            #pragma unroll
            for (int j = 0; j < 8; ++j)
                accL = __builtin_amdgcn_mfma_f32_16x16x32_bf16(a[j], wreg[j], accL, 0, 0, 0);
        }

        part[w][0][lane] = acc0; part[w][1][lane] = acc1;
        part[w][2][lane] = acc2; part[w][3][lane] = acc3;
        if (duty) partL[w][lane] = accL;
        __syncthreads();

        if (w < 4) {
            // reduce K-split partials for tile n=w, then epilogue
            f32x4 s = part[0][w][lane];
            #pragma unroll
            for (int k = 1; k < 8; ++k) s += part[k][w][lane];
            float hv[4];
            #pragma unroll
            for (int r = 0; r < 4; ++r) {
                float v = s[r] + pEp[r];
                v = fminf(fmaxf(v, -15.f), 15.f);
                float e2 = __expf(2.f * v);
                hv[r] = (e2 - 1.f) / (e2 + 1.f);   // tanh
            }
            // pack lane pairs (cols ccol, ccol+1) into one 4B coherent store
            #pragma unroll
            for (int r = 0; r < 4; ++r) {
                float other = __shfl_xor(hv[r], 1, 64);
                if ((lane & 1) == 0) {
                    const int row = r0 + q * 4 + r;
                    unsigned int pk = (unsigned int)f2bf(hv[r])
                                    | ((unsigned int)f2bf(other) << 16);
                    __hip_atomic_store(
                        (unsigned int*)(hn + (size_t)row * HH + ccol), pk,
                        __ATOMIC_RELAXED, __HIP_MEMORY_SCOPE_AGENT);
                    if (t == LL - 1) {
                        float2 fo; fo.x = hv[r]; fo.y = other;
                        *(float2*)(out_final + (size_t)row * HH + ccol) = fo;
                    }
                }
            }
            // join: my stores are at L3 (vmcnt drain), then count arrivals in
            // LDS; the 4th wave publishes the single per-block flag.
            asm volatile("s_waitcnt vmcnt(0)" ::: "memory");
            if (lane == 0) {
                unsigned int old = atomicAdd(&pcnt, 1u);
                if (old == 4u * (unsigned int)t + 3u)
                    __hip_atomic_store(flw, (unsigned int)(t + 1),
                                       __ATOMIC_RELAXED,
                                       __HIP_MEMORY_SCOPE_AGENT);
            }
        } else if (w == 4 && duty && t > 0) {
            // logits for position t-1 (normal stores, host-visible at exit)
            f32x4 s = partL[0][lane];
            #pragma unroll
            for (int k = 1; k < 8; ++k) s += partL[k][lane];
            const int lcol = cb * 16 + col;
            const float by = b_y[lcol];
            #pragma unroll
            for (int r = 0; r < 4; ++r) {
                const int row = r0 + q * 4 + r;
                out_logits[(size_t)row * (LL * VV) + (size_t)(t - 1) * VV + lcol]
                    = s[r] + by;
            }
        }

        __syncthreads();   // protect part[] WAR for next iteration
    }

    // final logits (position LL-1) from h_512, which sits in ping buffer 0
    if (duty) {
        wait_flags(flr, (unsigned int)LL, lane);   // producers' step-511 done
        const unsigned long long* Ap =
            (const unsigned long long*)(hbuf + (size_t)am * HH);
        bf16x8 a[8];
        #pragma unroll
        for (int j = 0; j < 8; ++j) {
            union { unsigned long long u[2]; bf16x8 v; } cv;
            const int base = ((w * 8 + j) * 4 + q) * 2;
            cv.u[0] = __hip_atomic_load(Ap + base,     __ATOMIC_RELAXED,
                                        __HIP_MEMORY_SCOPE_AGENT);
            cv.u[1] = __hip_atomic_load(Ap + base + 1, __ATOMIC_RELAXED,
                                        __HIP_MEMORY_SCOPE_AGENT);
            a[j] = cv.v;
        }
        f32x4 accL = {0.f,0.f,0.f,0.f};
        #pragma unroll
        for (int j = 0; j < 8; ++j)
            accL = __builtin_amdgcn_mfma_f32_16x16x32_bf16(a[j], wreg[j], accL, 0, 0, 0);
        partL[w][lane] = accL;
        __syncthreads();
        if (w == 4) {
            f32x4 s = partL[0][lane];
            #pragma unroll
            for (int k = 1; k < 8; ++k) s += partL[k][lane];
            const int lcol = cb * 16 + col;
            const float by = b_y[lcol];
            #pragma unroll
            for (int r = 0; r < 4; ++r) {
                const int row = r0 + q * 4 + r;
                out_logits[(size_t)row * (LL * VV) + (size_t)(LL - 1) * VV + lcol]
                    = s[r] + by;
            }
        }
    }
}

extern "C" void kernel_launch(void* const* d_in, const int* in_sizes, int n_in,
                              void* d_out, int out_size, void* d_ws, size_t ws_size,
                              hipStream_t stream) {
    const int*   x      = (const int*)  d_in[0];
    const float* hidden = (const float*)d_in[1];
    const float* emb    = (const float*)d_in[2];
    const float* W_xh   = (const float*)d_in[3];
    const float* W_hh   = (const float*)d_in[4];
    const float* b_h    = (const float*)d_in[5];
    const float* W_hy   = (const float*)d_in[6];
    const float* b_y    = (const float*)d_in[7];

    float* out_logits = (float*)d_out;                          // [B][L][V]
    float* out_final  = out_logits + (size_t)BB * LL * VV;      // [B][H]

    // workspace (~10.66 MB): whh_frag 8 MB | why_frag 384 KB | projE 768 KB |
    // h ping-pong 1 MB | spread per-block flags 32 KB
    char* ws = (char*)d_ws;
    unsigned short* w_hh_frag = (unsigned short*)ws;
    unsigned short* w_hy_frag = (unsigned short*)(ws + 8388608);
    float*          projE     = (float*)        (ws + 8388608 + 393216);
    unsigned short* hbuf      = (unsigned short*)(ws + 8388608 + 393216 + 786432);
    unsigned int*   bar       = (unsigned int*) (ws + 8388608 + 393216 + 786432 + 1048576);

    setup_kernel<<<dim3(1024), dim3(256), 0, stream>>>(
        x, hidden, emb, W_xh, W_hh, b_h, W_hy,
        projE, w_hh_frag, w_hy_frag, hbuf, bar);

    void* args[] = { (void*)&x, (void*)&projE, (void*)&w_hh_frag, (void*)&w_hy_frag,
                     (void*)&b_y, (void*)&hbuf, (void*)&out_logits, (void*)&out_final,
                     (void*)&bar };
    hipLaunchCooperativeKernel((void*)rnn_persist, dim3(256), dim3(512),
                               args, 0, stream);
}

// Round 9
// 2596.071 us; speedup vs baseline: 6.7364x; 1.1553x over previous
//
#include <hip/hip_runtime.h>

#define BB 128   // batch
#define LL 512   // seq len
#define HH 2048  // hidden
#define EE 128   // embed
#define VV 96    // vocab
#define BBHH (BB * HH)

// flag spreading: one flag per 128B line (32 words)
#define FSTRIDE 32

typedef short bf16x8 __attribute__((ext_vector_type(8)));
typedef float f32x4 __attribute__((ext_vector_type(4)));

__device__ __forceinline__ unsigned short f2bf(float f) {
    union { float f; unsigned int u; } c; c.f = f;
    unsigned int u = c.u;
    return (unsigned short)((u + 0x7FFFu + ((u >> 16) & 1u)) >> 16);  // RNE
}

// ---------------------------------------------------------------------------
// Setup: identical packing to the proven kernel (W_hh / W_hy -> MFMA-B
// fragment-linear bf16 tiles; projE fp32; h0 -> bf16) + zero the spread
// per-BLOCK flag array (256 flags x 32-word stride = 8192 words = 32 KB).
// ---------------------------------------------------------------------------
__global__ __launch_bounds__(256)
void setup_kernel(const int* __restrict__ x, const float* __restrict__ hidden,
                  const float* __restrict__ emb, const float* __restrict__ W_xh,
                  const float* __restrict__ W_hh, const float* __restrict__ b_h,
                  const float* __restrict__ W_hy,
                  float* __restrict__ projE,
                  unsigned short* __restrict__ w_hh_frag,
                  unsigned short* __restrict__ w_hy_frag,
                  unsigned short* __restrict__ hbuf,
                  unsigned int* __restrict__ bar)
{
    const int gtid = blockIdx.x * 256 + threadIdx.x;
    const int GT   = gridDim.x * 256;

    if (gtid < 256 * FSTRIDE) bar[gtid] = 0u;   // flags, reset every run

    for (int idx = gtid; idx < HH * HH; idx += GT) {
        int tile = idx >> 15;
        int rem  = idx & 32767;
        int c    = rem >> 3;
        int j    = rem & 7;
        int l    = c & 63;
        int i    = c >> 6;
        int row  = tile * 16 + (l & 15);
        int k    = i * 32 + (l >> 4) * 8 + j;
        w_hh_frag[idx] = f2bf(W_hh[(size_t)row * HH + k]);
    }
    for (int idx = gtid; idx < VV * HH; idx += GT) {
        int tile = idx >> 15;
        int rem  = idx & 32767;
        int c    = rem >> 3;
        int j    = rem & 7;
        int l    = c & 63;
        int i    = c >> 6;
        int row  = tile * 16 + (l & 15);
        int k    = i * 32 + (l >> 4) * 8 + j;
        w_hy_frag[idx] = f2bf(W_hy[(size_t)row * HH + k]);
    }
    for (int i = gtid; i < VV * HH; i += GT) {
        int v  = i >> 11;
        int hc = i & (HH - 1);
        const float4* ep = (const float4*)(emb + (size_t)v * EE);
        const float4* wp = (const float4*)(W_xh + (size_t)hc * EE);
        float s = b_h[hc];
        #pragma unroll 8
        for (int e = 0; e < EE / 4; ++e) {
            float4 a = ep[e], b = wp[e];
            s += a.x * b.x + a.y * b.y + a.z * b.z + a.w * b.w;
        }
        projE[i] = s;
    }
    for (int i = gtid; i < BBHH; i += GT) hbuf[i] = f2bf(hidden[i]);
}

// poll 4 producer-BLOCK flags (lane i < 4 owns one, each on its own 128B
// line) until all >= tgt. Branch dependence + compiler fence order the
// subsequent data loads; no HW acquire fence (would emit buffer_inv).
__device__ __forceinline__ void wait_flags(const unsigned int* fl,
                                           unsigned int tgt, int lane)
{
    if (lane < 4) {
        while (__hip_atomic_load(fl + lane * FSTRIDE, __ATOMIC_RELAXED,
                                 __HIP_MEMORY_SCOPE_AGENT) < tgt)
            __builtin_amdgcn_s_sleep(1);
    }
    asm volatile("" ::: "memory");
}

// A-fragment load: 8 x 16B coherent (sc1, L2-bypass -> L3) loads, stride
// 64B, self-draining. Halves the sc1 message count vs 2x8B atomic loads --
// the round-8 residual theory (coherence-point request-rate limit).
// "memory" clobber orders it after the flag-poll atomics.
__device__ __forceinline__ void lda8_sc1(const char* p, bf16x8 a[8]) {
    asm volatile(
        "global_load_dwordx4 %0, %8, off sc1\n\t"
        "global_load_dwordx4 %1, %8, off offset:64 sc1\n\t"
        "global_load_dwordx4 %2, %8, off offset:128 sc1\n\t"
        "global_load_dwordx4 %3, %8, off offset:192 sc1\n\t"
        "global_load_dwordx4 %4, %8, off offset:256 sc1\n\t"
        "global_load_dwordx4 %5, %8, off offset:320 sc1\n\t"
        "global_load_dwordx4 %6, %8, off offset:384 sc1\n\t"
        "global_load_dwordx4 %7, %8, off offset:448 sc1\n\t"
        "s_waitcnt vmcnt(0)"
        : "=&v"(a[0]), "=&v"(a[1]), "=&v"(a[2]), "=&v"(a[3]),
          "=&v"(a[4]), "=&v"(a[5]), "=&v"(a[6]), "=&v"(a[7])
        : "v"(p) : "memory");
}

// ---------------------------------------------------------------------------
// Persistent cooperative kernel, v6 = round-8 + 16B A-loads.
// Decomposition unchanged (group g = 16 batch rows, 32 col-blocks x 64 cols,
// 8-wave K-split, W_hh in VGPRs, h ping-pong sc1-coherent at L3).
// Sync unchanged: ONE epoch flag per producer block (LDS atomicAdd join,
// 4th reducer wave publishes); consumer wave w polls 4 flags.
// Safety (same as round 3/7/8): block flag = t implies its 4 reducer waves
// passed step t-1's first __syncthreads (joining all 8 waves' A-reads of
// h_{t-2}) AND each drained its own h-stores (vmcnt(0)) before the LDS add;
// the 4th add's return orders the flag store after all of them. Consumer
// union over its 8 waves covers all 32 producer blocks before any h_{t+1}
// write (first __syncthreads of the next step).
// ---------------------------------------------------------------------------
__global__ __launch_bounds__(512, 2)
void rnn_persist(const int* __restrict__ x, const float* __restrict__ projE,
                 const unsigned short* __restrict__ w_hh_frag,
                 const unsigned short* __restrict__ w_hy_frag,
                 const float* __restrict__ b_y,
                 unsigned short* __restrict__ hbuf,
                 float* __restrict__ out_logits, float* __restrict__ out_final,
                 unsigned int* __restrict__ bar)
{
    const int tid  = threadIdx.x;
    const int bid  = blockIdx.x;
    const int g    = bid >> 5;        // group 0..7 (16 batch rows)
    const int cb   = bid & 31;        // col-block 0..31 (64 hidden cols)
    const int r0   = g * 16;
    const int c0   = cb * 64;

    const int w    = tid >> 6;        // wave 0..7 = K-split index
    const int lane = tid & 63;
    const int col  = lane & 15;
    const int q    = lane >> 4;
    const int am   = r0 + col;        // A-fragment row (batch index)

    const bool duty = (cb < 6);

    __shared__ f32x4 part [8][4][64]; // 32 KB h partials
    __shared__ f32x4 partL[8][64];    //  8 KB logits partials
    __shared__ unsigned int pcnt;     // producer-wave join counter (monotonic)

    // ---- persistent W_hh fragments in registers (static indexing only) ----
    bf16x8 breg[4][8];
    {
        const bf16x8* Wc = (const bf16x8*)w_hh_frag;
        #pragma unroll
        for (int n = 0; n < 4; ++n) {
            const bf16x8* Bt = Wc + (size_t)(cb * 4 + n) * 4096 + lane;
            #pragma unroll
            for (int j = 0; j < 8; ++j) breg[n][j] = Bt[(w * 8 + j) * 64];
        }
    }
    bf16x8 wreg[8];
    if (duty) {
        const bf16x8* Bt = (const bf16x8*)w_hy_frag + (size_t)cb * 4096 + lane;
        #pragma unroll
        for (int j = 0; j < 8; ++j) wreg[j] = Bt[(w * 8 + j) * 64];
    }

    if (tid == 0) pcnt = 0u;
    __syncthreads();

    // consumer: 4 per-block flag lines (producer blocks 4w..4w+3 of group g)
    const unsigned int* flr = bar + (size_t)(g * 32 + 4 * w) * FSTRIDE;
    // producer: this block's single flag line
    unsigned int* flw = bar + (size_t)(g * 32 + cb) * FSTRIDE;

    for (int t = 0; t < LL; ++t) {
        const unsigned short* hp = hbuf + (size_t)(t & 1) * BBHH;
        unsigned short*       hn = hbuf + (size_t)((t + 1) & 1) * BBHH;

        // ---- epilogue operand prefetch (independent of h_t) ----
        int   tokp[4];
        float pEp[4];
        const int ccol = c0 + w * 16 + col;
        if (w < 4) {
            #pragma unroll
            for (int r = 0; r < 4; ++r) {
                const int row = r0 + q * 4 + r;
                tokp[r] = x[(size_t)row * LL + t];
            }
            #pragma unroll
            for (int r = 0; r < 4; ++r)
                pEp[r] = projE[(size_t)tokp[r] * HH + ccol];
        }

        // ---- wait for this wave's 4 producer blocks (fan-in 4) ----
        wait_flags(flr, (unsigned int)t, lane);

        // ---- A fragments via coherent 16B sc1 loads from L3 ----
        const char* Abase = (const char*)hp + (size_t)am * HH * 2
                          + w * 512 + q * 16;
        bf16x8 a[8];
        lda8_sc1(Abase, a);

        f32x4 acc0 = {0.f,0.f,0.f,0.f}, acc1 = {0.f,0.f,0.f,0.f};
        f32x4 acc2 = {0.f,0.f,0.f,0.f}, acc3 = {0.f,0.f,0.f,0.f};
        f32x4 accL = {0.f,0.f,0.f,0.f};
        #pragma unroll
        for (int j = 0; j < 8; ++j) {   // 4 independent chains of 8
            acc0 = __builtin_amdgcn_mfma_f32_16x16x32_bf16(a[j], breg[0][j], acc0, 0, 0, 0);
            acc1 = __builtin_amdgcn_mfma_f32_16x16x32_bf16(a[j], breg[1][j], acc1, 0, 0, 0);
            acc2 = __builtin_amdgcn_mfma_f32_16x16x32_bf16(a[j], breg[2][j], acc2, 0, 0, 0);
            acc3 = __builtin_amdgcn_mfma_f32_16x16x32_bf16(a[j], breg[3][j], acc3, 0, 0, 0);
        }
        if (duty) {
            #pragma unroll
            for (int j = 0; j < 8; ++j)
                accL = __builtin_amdgcn_mfma_f32_16x16x32_bf16(a[j], wreg[j], accL, 0, 0, 0);
        }

        part[w][0][lane] = acc0; part[w][1][lane] = acc1;
        part[w][2][lane] = acc2; part[w][3][lane] = acc3;
        if (duty) partL[w][lane] = accL;
        __syncthreads();

        if (w < 4) {
            // reduce K-split partials for tile n=w, then epilogue
            f32x4 s = part[0][w][lane];
            #pragma unroll
            for (int k = 1; k < 8; ++k) s += part[k][w][lane];
            float hv[4];
            #pragma unroll
            for (int r = 0; r < 4; ++r) {
                float v = s[r] + pEp[r];
                v = fminf(fmaxf(v, -15.f), 15.f);
                float e2 = __expf(2.f * v);
                hv[r] = (e2 - 1.f) / (e2 + 1.f);   // tanh
            }
            // pack lane pairs (cols ccol, ccol+1) into one 4B coherent store
            #pragma unroll
            for (int r = 0; r < 4; ++r) {
                float other = __shfl_xor(hv[r], 1, 64);
                if ((lane & 1) == 0) {
                    const int row = r0 + q * 4 + r;
                    unsigned int pk = (unsigned int)f2bf(hv[r])
                                    | ((unsigned int)f2bf(other) << 16);
                    __hip_atomic_store(
                        (unsigned int*)(hn + (size_t)row * HH + ccol), pk,
                        __ATOMIC_RELAXED, __HIP_MEMORY_SCOPE_AGENT);
                    if (t == LL - 1) {
                        float2 fo; fo.x = hv[r]; fo.y = other;
                        *(float2*)(out_final + (size_t)row * HH + ccol) = fo;
                    }
                }
            }
            // join: my stores are at L3 (vmcnt drain), then count arrivals in
            // LDS; the 4th wave publishes the single per-block flag.
            asm volatile("s_waitcnt vmcnt(0)" ::: "memory");
            if (lane == 0) {
                unsigned int old = atomicAdd(&pcnt, 1u);
                if (old == 4u * (unsigned int)t + 3u)
                    __hip_atomic_store(flw, (unsigned int)(t + 1),
                                       __ATOMIC_RELAXED,
                                       __HIP_MEMORY_SCOPE_AGENT);
            }
        } else if (w == 4 && duty && t > 0) {
            // logits for position t-1 (normal stores, host-visible at exit)
            f32x4 s = partL[0][lane];
            #pragma unroll
            for (int k = 1; k < 8; ++k) s += partL[k][lane];
            const int lcol = cb * 16 + col;
            const float by = b_y[lcol];
            #pragma unroll
            for (int r = 0; r < 4; ++r) {
                const int row = r0 + q * 4 + r;
                out_logits[(size_t)row * (LL * VV) + (size_t)(t - 1) * VV + lcol]
                    = s[r] + by;
            }
        }

        __syncthreads();   // protect part[] WAR for next iteration
    }

    // final logits (position LL-1) from h_512, which sits in ping buffer 0
    if (duty) {
        wait_flags(flr, (unsigned int)LL, lane);   // producers' step-511 done
        const char* Abase = (const char*)hbuf + (size_t)am * HH * 2
                          + w * 512 + q * 16;
        bf16x8 a[8];
        lda8_sc1(Abase, a);
        f32x4 accL = {0.f,0.f,0.f,0.f};
        #pragma unroll
        for (int j = 0; j < 8; ++j)
            accL = __builtin_amdgcn_mfma_f32_16x16x32_bf16(a[j], wreg[j], accL, 0, 0, 0);
        partL[w][lane] = accL;
        __syncthreads();
        if (w == 4) {
            f32x4 s = partL[0][lane];
            #pragma unroll
            for (int k = 1; k < 8; ++k) s += partL[k][lane];
            const int lcol = cb * 16 + col;
            const float by = b_y[lcol];
            #pragma unroll
            for (int r = 0; r < 4; ++r) {
                const int row = r0 + q * 4 + r;
                out_logits[(size_t)row * (LL * VV) + (size_t)(LL - 1) * VV + lcol]
                    = s[r] + by;
            }
        }
    }
}

extern "C" void kernel_launch(void* const* d_in, const int* in_sizes, int n_in,
                              void* d_out, int out_size, void* d_ws, size_t ws_size,
                              hipStream_t stream) {
    const int*   x      = (const int*)  d_in[0];
    const float* hidden = (const float*)d_in[1];
    const float* emb    = (const float*)d_in[2];
    const float* W_xh   = (const float*)d_in[3];
    const float* W_hh   = (const float*)d_in[4];
    const float* b_h    = (const float*)d_in[5];
    const float* W_hy   = (const float*)d_in[6];
    const float* b_y    = (const float*)d_in[7];

    float* out_logits = (float*)d_out;                          // [B][L][V]
    float* out_final  = out_logits + (size_t)BB * LL * VV;      // [B][H]

    // workspace (~10.66 MB): whh_frag 8 MB | why_frag 384 KB | projE 768 KB |
    // h ping-pong 1 MB | spread per-block flags 32 KB
    char* ws = (char*)d_ws;
    unsigned short* w_hh_frag = (unsigned short*)ws;
    unsigned short* w_hy_frag = (unsigned short*)(ws + 8388608);
    float*          projE     = (float*)        (ws + 8388608 + 393216);
    unsigned short* hbuf      = (unsigned short*)(ws + 8388608 + 393216 + 786432);
    unsigned int*   bar       = (unsigned int*) (ws + 8388608 + 393216 + 786432 + 1048576);

    setup_kernel<<<dim3(1024), dim3(256), 0, stream>>>(
        x, hidden, emb, W_xh, W_hh, b_h, W_hy,
        projE, w_hh_frag, w_hy_frag, hbuf, bar);

    void* args[] = { (void*)&x, (void*)&projE, (void*)&w_hh_frag, (void*)&w_hy_frag,
                     (void*)&b_y, (void*)&hbuf, (void*)&out_logits, (void*)&out_final,
                     (void*)&bar };
    hipLaunchCooperativeKernel((void*)rnn_persist, dim3(256), dim3(512),
                               args, 0, stream);
}